// Round 1
// baseline (42.555 us; speedup 1.0000x reference)
//
#include <hip/hip_runtime.h>
#include <math.h>

#define BATCH 128
#define N_IN 2048
#define N_OUT 1024
#define MAXK 64
#define TEMP 0.1f
#define INV_TEMP 10.0f
#define NEG_FILL -1.0e9f

__device__ __forceinline__ unsigned int f2key(float f) {
    unsigned int b = __float_as_uint(f);
    return (b & 0x80000000u) ? ~b : (b | 0x80000000u);
}
__device__ __forceinline__ float key2f(unsigned int u) {
    unsigned int b = (u & 0x80000000u) ? (u & 0x7FFFFFFFu) : ~u;
    return __uint_as_float(b);
}

// Kernel 1: per-batch-row exact rank-1023 element (lower median) via 8-bit
// radix select on monotonic uint keys, then write gated_x.
__global__ __launch_bounds__(256) void k_median_gate(const float* __restrict__ x,
                                                     float* __restrict__ gx) {
    __shared__ unsigned int keys[N_IN];
    __shared__ unsigned int hist[256];
    __shared__ unsigned int scan[256];
    __shared__ unsigned int sel_bin, sel_rank;

    const int b = blockIdx.x;
    const int tid = threadIdx.x;
    const float* row = x + (size_t)b * N_IN;

    float vals[8];
#pragma unroll
    for (int j = 0; j < 8; ++j) {
        int i = tid + j * 256;
        float v = row[i];
        vals[j] = v;
        keys[i] = f2key(v);
    }

    unsigned int prefix = 0;
    unsigned int k = (N_IN - 1) / 2;  // 1023: rank of the lower median

    for (int pos = 24; pos >= 0; pos -= 8) {
        hist[tid] = 0;
        __syncthreads();
        unsigned int hmask = (pos == 24) ? 0u : (0xFFFFFFFFu << (pos + 8));
#pragma unroll
        for (int j = 0; j < 8; ++j) {
            unsigned int u = keys[tid + j * 256];
            if ((u & hmask) == (prefix & hmask)) {
                atomicAdd(&hist[(u >> pos) & 0xFFu], 1u);
            }
        }
        __syncthreads();
        // Hillis-Steele inclusive scan over 256 bins
        unsigned int v = hist[tid];
        scan[tid] = v;
        __syncthreads();
        for (int off = 1; off < 256; off <<= 1) {
            unsigned int t = (tid >= off) ? scan[tid - off] : 0u;
            __syncthreads();
            scan[tid] += t;
            __syncthreads();
        }
        unsigned int incl = scan[tid];
        unsigned int excl = incl - hist[tid];
        if (k >= excl && k < incl) {  // exactly one thread matches
            sel_bin = (unsigned int)tid;
            sel_rank = k - excl;
        }
        __syncthreads();
        prefix |= (sel_bin << pos);
        k = sel_rank;
        __syncthreads();
    }

    const float med = key2f(prefix);
#pragma unroll
    for (int j = 0; j < 8; ++j) {
        int i = tid + j * 256;
        float v = vals[j];
        gx[(size_t)b * N_IN + i] = (fabsf(v - med) < 1.0f) ? v : 0.0f;
    }
}

// Kernel 2: per-output-row compaction of active synapse indices + weights.
__global__ __launch_bounds__(256) void k_compact(const float* __restrict__ w,
                                                 const float* __restrict__ msk,
                                                 int* __restrict__ cnt,
                                                 int* __restrict__ gidx,
                                                 float* __restrict__ gwv) {
    __shared__ int lcnt;
    __shared__ int lidx[MAXK];
    __shared__ float lwv[MAXK];

    const int o = blockIdx.x;
    const int tid = threadIdx.x;
    if (tid == 0) lcnt = 0;
    __syncthreads();

    const float* mr = msk + (size_t)o * N_IN;
    const float* wr = w + (size_t)o * N_IN;
#pragma unroll
    for (int j = 0; j < 8; ++j) {
        int i = tid + j * 256;
        if (mr[i] != 0.0f) {
            int p = atomicAdd(&lcnt, 1);
            if (p < MAXK) {
                lidx[p] = i;
                lwv[p] = wr[i];
            }
        }
    }
    __syncthreads();
    int c = lcnt;
    if (tid == 0) cnt[o] = c;
    if (tid < c && tid < MAXK) {
        gidx[o * MAXK + tid] = lidx[tid];
        gwv[o * MAXK + tid] = lwv[tid];
    }
}

// Kernel 3: out[b,o] = T * logsumexp over active i of (gx[b,i]+w[o,i])/T
__global__ __launch_bounds__(256) void k_lse(const float* __restrict__ gx,
                                             const int* __restrict__ cnt,
                                             const int* __restrict__ gidx,
                                             const float* __restrict__ gwv,
                                             const float* __restrict__ w,
                                             const float* __restrict__ msk,
                                             float* __restrict__ out) {
    __shared__ float sgx[N_IN];
    const int b = blockIdx.x;
    const int tid = threadIdx.x;
#pragma unroll
    for (int j = 0; j < 8; ++j) {
        int i = tid + j * 256;
        sgx[i] = gx[(size_t)b * N_IN + i];
    }
    __syncthreads();

    for (int o = tid; o < N_OUT; o += 256) {
        int c = cnt[o];
        float res;
        if (c == 0) {
            // all entries NEG_FILL: T*(-1e10 + log(2048)) rounds to -1e9 in f32
            res = NEG_FILL;
        } else if (c <= MAXK) {
            const int* ip = gidx + o * MAXK;
            const float* wp = gwv + o * MAXK;
            float mx = -INFINITY;
            for (int j = 0; j < c; ++j) {
                float v = (sgx[ip[j]] + wp[j]) * INV_TEMP;
                mx = fmaxf(mx, v);
            }
            float s = 0.0f;
            for (int j = 0; j < c; ++j) {
                float v = (sgx[ip[j]] + wp[j]) * INV_TEMP;
                s += expf(v - mx);
            }
            res = TEMP * (mx + logf(s));
        } else {
            // safety fallback (count overflow, statistically impossible here)
            const float* mr = msk + (size_t)o * N_IN;
            const float* wr = w + (size_t)o * N_IN;
            float mx = -INFINITY;
            for (int i = 0; i < N_IN; ++i)
                if (mr[i] != 0.0f) mx = fmaxf(mx, (sgx[i] + wr[i]) * INV_TEMP);
            float s = 0.0f;
            for (int i = 0; i < N_IN; ++i)
                if (mr[i] != 0.0f) s += expf((sgx[i] + wr[i]) * INV_TEMP - mx);
            res = TEMP * (mx + logf(s));
        }
        out[(size_t)b * N_OUT + o] = res;
    }
}

extern "C" void kernel_launch(void* const* d_in, const int* in_sizes, int n_in,
                              void* d_out, int out_size, void* d_ws, size_t ws_size,
                              hipStream_t stream) {
    const float* x = (const float*)d_in[0];
    const float* w = (const float*)d_in[1];
    const float* msk = (const float*)d_in[2];
    float* out = (float*)d_out;

    float* gx = (float*)d_ws;                       // BATCH*N_IN floats
    int* cnt = (int*)(gx + (size_t)BATCH * N_IN);   // N_OUT ints
    int* gidx = cnt + N_OUT;                        // N_OUT*MAXK ints
    float* gwv = (float*)(gidx + (size_t)N_OUT * MAXK);  // N_OUT*MAXK floats

    hipLaunchKernelGGL(k_median_gate, dim3(BATCH), dim3(256), 0, stream, x, gx);
    hipLaunchKernelGGL(k_compact, dim3(N_OUT), dim3(256), 0, stream, w, msk, cnt, gidx, gwv);
    hipLaunchKernelGGL(k_lse, dim3(BATCH), dim3(256), 0, stream, gx, cnt, gidx, gwv, w, msk, out);
}

// Round 2
// 23.061 us; speedup vs baseline: 1.8454x; 1.8454x over previous
//
#include <hip/hip_runtime.h>
#include <math.h>

#define BATCH 128
#define N_IN 2048
#define N_OUT 1024
#define MAXK 64
#define TEMP 0.1f
#define INV_TEMP 10.0f
#define NEG_FILL -1.0e9f

__device__ __forceinline__ unsigned int f2key(float f) {
    unsigned int b = __float_as_uint(f);
    return (b & 0x80000000u) ? ~b : (b | 0x80000000u);
}
__device__ __forceinline__ float key2f(unsigned int u) {
    unsigned int b = (u & 0x80000000u) ? (u & 0x7FFFFFFFu) : ~u;
    return __uint_as_float(b);
}

// Kernel A: per-output-row compaction of active synapses into (idx, w) pairs.
// Deterministic order (thread-major) via shfl-scan — no atomics.
__global__ __launch_bounds__(256) void k_compact(const float* __restrict__ w,
                                                 const float* __restrict__ msk,
                                                 int* __restrict__ cnt,
                                                 int2* __restrict__ lists) {
    const int o = blockIdx.x;
    const int tid = threadIdx.x;
    const float4* wr = (const float4*)(w + (size_t)o * N_IN);
    const float4* mr = (const float4*)(msk + (size_t)o * N_IN);
    float4 wa = wr[tid], wb = wr[tid + 256];
    float4 ma = mr[tid], mb = mr[tid + 256];
    float wv[8] = {wa.x, wa.y, wa.z, wa.w, wb.x, wb.y, wb.z, wb.w};
    float mv[8] = {ma.x, ma.y, ma.z, ma.w, mb.x, mb.y, mb.z, mb.w};

    int myc = 0;
#pragma unroll
    for (int j = 0; j < 8; ++j) myc += (mv[j] != 0.0f);

    // inclusive scan of myc across 256 threads: wave shfl + LDS wave sums
    const int lane = tid & 63;
    const int wid = tid >> 6;
    int sv = myc;
#pragma unroll
    for (int off = 1; off < 64; off <<= 1) {
        int t = __shfl_up(sv, off, 64);
        if (lane >= off) sv += t;
    }
    __shared__ int wsum4[4];
    if (lane == 63) wsum4[wid] = sv;
    __syncthreads();
    int base = 0;
    for (int ww = 0; ww < wid; ++ww) base += wsum4[ww];
    const int incl = sv + base;
    const int excl = incl - myc;
    if (tid == 255) cnt[o] = incl;  // total actives this row

    int p = excl;
#pragma unroll
    for (int j = 0; j < 8; ++j) {
        if (mv[j] != 0.0f) {
            if (p < MAXK) {
                int idx = (j < 4) ? 4 * tid + j : 1024 + 4 * tid + (j - 4);
                lists[o * MAXK + p] = make_int2(idx, __float_as_int(wv[j]));
            }
            ++p;
        }
    }
}

// Kernel B (fused): exact lower-median via 4-pass radix select (wave-shfl
// scans), gate into LDS, then sparse logsumexp over compacted synapse lists.
// grid = BATCH*4; block handles batch (blockIdx>>2), output quarter (blockIdx&3).
__global__ __launch_bounds__(256) void k_fused(const float* __restrict__ x,
                                               const int* __restrict__ cnt,
                                               const int2* __restrict__ lists,
                                               const float* __restrict__ w,
                                               const float* __restrict__ msk,
                                               float* __restrict__ out) {
    __shared__ float sgx[N_IN];
    __shared__ unsigned int hist[256];
    __shared__ unsigned int wsum4[4];
    __shared__ unsigned int sel[2];

    const int b = blockIdx.x >> 2;
    const int oq = blockIdx.x & 3;
    const int tid = threadIdx.x;
    const int lane = tid & 63;
    const int wwid = tid >> 6;

    const float4* xr = (const float4*)(x + (size_t)b * N_IN);
    float4 va = xr[tid], vb = xr[tid + 256];
    float vals[8] = {va.x, va.y, va.z, va.w, vb.x, vb.y, vb.z, vb.w};

    // exact rank-1023 (lower median) radix select, 8 bits per pass
    unsigned int prefix = 0;
    unsigned int k = (N_IN - 1) / 2;  // 1023
    for (int pos = 24; pos >= 0; pos -= 8) {
        hist[tid] = 0;
        __syncthreads();
        const unsigned int hmask = (pos == 24) ? 0u : (0xFFFFFFFFu << (pos + 8));
#pragma unroll
        for (int j = 0; j < 8; ++j) {
            unsigned int u = f2key(vals[j]);
            if ((u & hmask) == (prefix & hmask))
                atomicAdd(&hist[(u >> pos) & 0xFFu], 1u);
        }
        __syncthreads();
        unsigned int v = hist[tid];
        unsigned int sv = v;
#pragma unroll
        for (int off = 1; off < 64; off <<= 1) {
            unsigned int t = __shfl_up(sv, off, 64);
            if (lane >= off) sv += t;
        }
        if (lane == 63) wsum4[wwid] = sv;
        __syncthreads();
        unsigned int base = 0;
        for (int ww = 0; ww < wwid; ++ww) base += wsum4[ww];
        const unsigned int incl = sv + base;
        const unsigned int excl = incl - v;
        if (k >= excl && k < incl) {  // exactly one thread matches
            sel[0] = (unsigned int)tid;
            sel[1] = k - excl;
        }
        __syncthreads();
        prefix |= sel[0] << pos;
        k = sel[1];
        __syncthreads();
    }
    const float med = key2f(prefix);

    // gate into LDS
#pragma unroll
    for (int j = 0; j < 8; ++j) {
        const int idx = (j < 4) ? 4 * tid + j : 1024 + 4 * tid + (j - 4);
        const float v = vals[j];
        sgx[idx] = (fabsf(v - med) < 1.0f) ? v : 0.0f;
    }
    __syncthreads();

    // sparse logsumexp: one output per thread
    const int o = oq * 256 + tid;
    const int c = cnt[o];
    float res;
    if (c == 0) {
        res = NEG_FILL;  // T*(-1e10 + log 2048) rounds to -1e9 in f32
    } else if (c <= MAXK) {
        const int2* lp = lists + o * MAXK;
        float mx = -INFINITY;
        for (int j = 0; j < c; ++j) {
            int2 e = lp[j];
            float v = (sgx[e.x] + __int_as_float(e.y)) * INV_TEMP;
            mx = fmaxf(mx, v);
        }
        float s = 0.0f;
        for (int j = 0; j < c; ++j) {
            int2 e = lp[j];
            float v = (sgx[e.x] + __int_as_float(e.y)) * INV_TEMP;
            s += __expf(v - mx);
        }
        res = TEMP * (mx + __logf(s));
    } else {
        // overflow fallback (statistically unreachable): dense masked pass
        const float* mr = msk + (size_t)o * N_IN;
        const float* wr = w + (size_t)o * N_IN;
        float mx = -INFINITY;
        for (int i = 0; i < N_IN; ++i)
            if (mr[i] != 0.0f) mx = fmaxf(mx, (sgx[i] + wr[i]) * INV_TEMP);
        float s = 0.0f;
        for (int i = 0; i < N_IN; ++i)
            if (mr[i] != 0.0f) s += __expf((sgx[i] + wr[i]) * INV_TEMP - mx);
        res = TEMP * (mx + __logf(s));
    }
    out[(size_t)b * N_OUT + o] = res;
}

extern "C" void kernel_launch(void* const* d_in, const int* in_sizes, int n_in,
                              void* d_out, int out_size, void* d_ws, size_t ws_size,
                              hipStream_t stream) {
    const float* x = (const float*)d_in[0];
    const float* w = (const float*)d_in[1];
    const float* msk = (const float*)d_in[2];
    float* out = (float*)d_out;

    int* cnt = (int*)d_ws;                      // N_OUT ints
    int2* lists = (int2*)(cnt + N_OUT);         // N_OUT*MAXK int2 (512 KB)

    hipLaunchKernelGGL(k_compact, dim3(N_OUT), dim3(256), 0, stream, w, msk, cnt, lists);
    hipLaunchKernelGGL(k_fused, dim3(BATCH * 4), dim3(256), 0, stream, x, cnt, lists, w, msk, out);
}

// Round 3
// 21.677 us; speedup vs baseline: 1.9632x; 1.0638x over previous
//
#include <hip/hip_runtime.h>
#include <math.h>

#define BATCH 128
#define N_IN 2048
#define N_OUT 1024
#define MAXK 40
#define TEMP 0.1f
#define INV_TEMP 10.0f
#define NEG_FILL -1.0e9f

__device__ __forceinline__ unsigned int f2key(float f) {
    unsigned int b = __float_as_uint(f);
    return (b & 0x80000000u) ? ~b : (b | 0x80000000u);
}
__device__ __forceinline__ float key2f(unsigned int u) {
    unsigned int b = (u & 0x80000000u) ? (u & 0x7FFFFFFFu) : ~u;
    return __uint_as_float(b);
}

// Prep kernel, grid = N_OUT + BATCH.
//  blocks [0, N_OUT): compact row o's active synapses into entry-major
//    listsT[j][o] = (idx, w_bits); deterministic order via shfl-scan.
//  blocks [N_OUT, N_OUT+BATCH): exact lower-median of x row via radix
//    select, write gated_x row to gx.
__global__ __launch_bounds__(256) void k_prep(const float* __restrict__ x,
                                              const float* __restrict__ w,
                                              const float* __restrict__ msk,
                                              int* __restrict__ cnt,
                                              int2* __restrict__ listsT,
                                              float* __restrict__ gx) {
    __shared__ unsigned int hist[256];
    __shared__ unsigned int wsum4[4];
    __shared__ unsigned int sel[2];

    const int tid = threadIdx.x;
    const int lane = tid & 63;
    const int wwid = tid >> 6;

    if ((int)blockIdx.x < N_OUT) {
        // ---------- compaction ----------
        const int o = blockIdx.x;
        const float4* wr = (const float4*)(w + (size_t)o * N_IN);
        const float4* mr = (const float4*)(msk + (size_t)o * N_IN);
        float4 wa = wr[tid], wb = wr[tid + 256];
        float4 ma = mr[tid], mb = mr[tid + 256];
        float wv[8] = {wa.x, wa.y, wa.z, wa.w, wb.x, wb.y, wb.z, wb.w};
        float mv[8] = {ma.x, ma.y, ma.z, ma.w, mb.x, mb.y, mb.z, mb.w};

        int myc = 0;
#pragma unroll
        for (int j = 0; j < 8; ++j) myc += (mv[j] != 0.0f);

        int sv = myc;
#pragma unroll
        for (int off = 1; off < 64; off <<= 1) {
            int t = __shfl_up(sv, off, 64);
            if (lane >= off) sv += t;
        }
        if (lane == 63) wsum4[wwid] = (unsigned int)sv;
        __syncthreads();
        int base = 0;
        for (int ww = 0; ww < wwid; ++ww) base += (int)wsum4[ww];
        const int incl = sv + base;
        const int excl = incl - myc;
        if (tid == 255) cnt[o] = incl;

        int p = excl;
#pragma unroll
        for (int j = 0; j < 8; ++j) {
            if (mv[j] != 0.0f) {
                if (p < MAXK) {
                    int idx = (j < 4) ? 4 * tid + j : 1024 + 4 * tid + (j - 4);
                    listsT[p * N_OUT + o] = make_int2(idx, __float_as_int(wv[j]));
                }
                ++p;
            }
        }
    } else {
        // ---------- median + gate ----------
        const int b = blockIdx.x - N_OUT;
        const float4* xr = (const float4*)(x + (size_t)b * N_IN);
        float4 va = xr[tid], vb = xr[tid + 256];
        float vals[8] = {va.x, va.y, va.z, va.w, vb.x, vb.y, vb.z, vb.w};

        unsigned int prefix = 0;
        unsigned int k = (N_IN - 1) / 2;  // 1023: lower median rank
        for (int pos = 24; pos >= 0; pos -= 8) {
            hist[tid] = 0;
            __syncthreads();
            const unsigned int hmask = (pos == 24) ? 0u : (0xFFFFFFFFu << (pos + 8));
#pragma unroll
            for (int j = 0; j < 8; ++j) {
                unsigned int u = f2key(vals[j]);
                if ((u & hmask) == (prefix & hmask))
                    atomicAdd(&hist[(u >> pos) & 0xFFu], 1u);
            }
            __syncthreads();
            unsigned int v = hist[tid];
            unsigned int sv = v;
#pragma unroll
            for (int off = 1; off < 64; off <<= 1) {
                unsigned int t = __shfl_up(sv, off, 64);
                if (lane >= off) sv += t;
            }
            if (lane == 63) wsum4[wwid] = sv;
            __syncthreads();
            unsigned int base = 0;
            for (int ww = 0; ww < wwid; ++ww) base += wsum4[ww];
            const unsigned int incl = sv + base;
            const unsigned int excl = incl - v;
            if (k >= excl && k < incl) {
                sel[0] = (unsigned int)tid;
                sel[1] = k - excl;
            }
            __syncthreads();
            prefix |= sel[0] << pos;
            k = sel[1];
            __syncthreads();
        }
        const float med = key2f(prefix);

        float4* gr = (float4*)(gx + (size_t)b * N_IN);
        float4 ga, gb;
        ga.x = (fabsf(vals[0] - med) < 1.0f) ? vals[0] : 0.0f;
        ga.y = (fabsf(vals[1] - med) < 1.0f) ? vals[1] : 0.0f;
        ga.z = (fabsf(vals[2] - med) < 1.0f) ? vals[2] : 0.0f;
        ga.w = (fabsf(vals[3] - med) < 1.0f) ? vals[3] : 0.0f;
        gb.x = (fabsf(vals[4] - med) < 1.0f) ? vals[4] : 0.0f;
        gb.y = (fabsf(vals[5] - med) < 1.0f) ? vals[5] : 0.0f;
        gb.z = (fabsf(vals[6] - med) < 1.0f) ? vals[6] : 0.0f;
        gb.w = (fabsf(vals[7] - med) < 1.0f) ? vals[7] : 0.0f;
        gr[tid] = ga;
        gr[tid + 256] = gb;
    }
}

// LSE kernel, grid = BATCH*4: block (b, oq); one output per thread.
__global__ __launch_bounds__(256) void k_lse(const float* __restrict__ gx,
                                             const int* __restrict__ cnt,
                                             const int2* __restrict__ listsT,
                                             const float* __restrict__ w,
                                             const float* __restrict__ msk,
                                             float* __restrict__ out) {
    __shared__ float sgx[N_IN];
    const int b = blockIdx.x >> 2;
    const int oq = blockIdx.x & 3;
    const int tid = threadIdx.x;

    const float4* xr = (const float4*)(gx + (size_t)b * N_IN);
    ((float4*)sgx)[tid] = xr[tid];
    ((float4*)sgx)[tid + 256] = xr[tid + 256];
    __syncthreads();

    const int o = oq * 256 + tid;
    const int c = cnt[o];
    float res;
    if (c == 0) {
        res = NEG_FILL;  // T*(-1e10 + log 2048) rounds to -1e9 in f32
    } else if (c <= MAXK) {
        float mx = -INFINITY;
        for (int j = 0; j < c; ++j) {  // coalesced: lanes stride 8B at each j
            int2 e = listsT[j * N_OUT + o];
            float v = (sgx[e.x] + __int_as_float(e.y)) * INV_TEMP;
            mx = fmaxf(mx, v);
        }
        float s = 0.0f;
        for (int j = 0; j < c; ++j) {
            int2 e = listsT[j * N_OUT + o];
            float v = (sgx[e.x] + __int_as_float(e.y)) * INV_TEMP;
            s += __expf(v - mx);
        }
        res = TEMP * (mx + __logf(s));
    } else {
        // overflow fallback (statistically near-unreachable): dense masked pass
        const float* mr = msk + (size_t)o * N_IN;
        const float* wr = w + (size_t)o * N_IN;
        float mx = -INFINITY;
        for (int i = 0; i < N_IN; ++i)
            if (mr[i] != 0.0f) mx = fmaxf(mx, (sgx[i] + wr[i]) * INV_TEMP);
        float s = 0.0f;
        for (int i = 0; i < N_IN; ++i)
            if (mr[i] != 0.0f) s += __expf((sgx[i] + wr[i]) * INV_TEMP - mx);
        res = TEMP * (mx + __logf(s));
    }
    out[(size_t)b * N_OUT + o] = res;
}

extern "C" void kernel_launch(void* const* d_in, const int* in_sizes, int n_in,
                              void* d_out, int out_size, void* d_ws, size_t ws_size,
                              hipStream_t stream) {
    const float* x = (const float*)d_in[0];
    const float* w = (const float*)d_in[1];
    const float* msk = (const float*)d_in[2];
    float* out = (float*)d_out;

    int* cnt = (int*)d_ws;                                  // N_OUT ints
    int2* listsT = (int2*)(cnt + N_OUT);                    // MAXK*N_OUT int2 (320 KB)
    float* gx = (float*)(listsT + (size_t)MAXK * N_OUT);    // BATCH*N_IN floats (1 MB)

    hipLaunchKernelGGL(k_prep, dim3(N_OUT + BATCH), dim3(256), 0, stream,
                       x, w, msk, cnt, listsT, gx);
    hipLaunchKernelGGL(k_lse, dim3(BATCH * 4), dim3(256), 0, stream,
                       gx, cnt, listsT, w, msk, out);
}